// Round 6
// baseline (126.048 us; speedup 1.0000x reference)
//
#include <hip/hip_runtime.h>

#define NBLOCKS 1024
#define NTHREADS 256

// Per-sample loss. DELTA = 1.0, CENSORING_WEIGHT = 1.0.
__device__ __forceinline__ float per_sample(float pe, float ps, float tg,
                                            float th, int bid, int cen) {
  float pred = (bid == 0) ? pe : ps;
  float d = fmaxf(th - pred, 0.0f);
  float closs = d * d;
  float ae = fabsf(pred - tg);
  float q = fminf(ae, 1.0f);
  float hub = 0.5f * q * q + (ae - q);
  return cen ? closs : hub;
}

__device__ __forceinline__ float proc4(const float4& e, const float4& s,
                                       const float4& t, const float4& h,
                                       const int4& b, int c0, int c1, int c2,
                                       int c3) {
  float a = per_sample(e.x, s.x, t.x, h.x, b.x, c0);
  a += per_sample(e.y, s.y, t.y, h.y, b.y, c1);
  a += per_sample(e.z, s.z, t.z, h.z, b.z, c2);
  a += per_sample(e.w, s.w, t.w, h.w, b.w, c3);
  return a;
}

// Single kernel: chunked contiguous per-block ranges (R4 win), 8 elems/thread
// per iter (2 consecutive float4 per array), in-wave layout probe (R3 win),
// last-block finalize via u32 ticket + plain partial stores + native f32
// atomic reads (R3 lesson: NO f64 CAS, NO same-address f32 add storm).
__global__ __launch_bounds__(NTHREADS, 4) void dualhead_fused(
    const float4* __restrict__ pe, const float4* __restrict__ ps,
    const float4* __restrict__ tg, const int4* __restrict__ bid,
    const void* __restrict__ cens, const float4* __restrict__ th,
    float* __restrict__ partials, unsigned* __restrict__ counter,
    float* __restrict__ out, int n, double inv_n) {
  // Layout probe: int32 {0,1} => high 3 bytes of every dword are 0.
  unsigned probe = ((const unsigned*)cens)[threadIdx.x & 63];
  const bool is8 = __ballot((probe & 0xFFFFFF00u) != 0) != 0ULL;

  const int nvec = n >> 2;
  const int vcnt = nvec / gridDim.x;      // vec4 per block chunk (4096)
  const int v0 = blockIdx.x * vcnt;
  const int per_iter = NTHREADS * 2;      // 512 vec4 per block-iter
  const int full = vcnt / per_iter;       // 8 full iters for N=16M

  float acc = 0.0f;
  int v = v0 + threadIdx.x * 2;           // two CONSECUTIVE vec4 per thread
  for (int it = 0; it < full; ++it, v += per_iter) {
    float4 e0 = pe[v], e1 = pe[v + 1];
    float4 s0 = ps[v], s1 = ps[v + 1];
    float4 t0 = tg[v], t1 = tg[v + 1];
    float4 h0 = th[v], h1 = th[v + 1];
    int4 b0 = bid[v], b1 = bid[v + 1];
    if (is8) {
      // 8 censored bytes for elements [4v, 4v+8): one 8B load.
      uint2 cc = *(const uint2*)((const char*)cens + ((size_t)v << 2));
      acc += proc4(e0, s0, t0, h0, b0, cc.x & 0xff, (cc.x >> 8) & 0xff,
                   (cc.x >> 16) & 0xff, (cc.x >> 24) & 0xff);
      acc += proc4(e1, s1, t1, h1, b1, cc.y & 0xff, (cc.y >> 8) & 0xff,
                   (cc.y >> 16) & 0xff, (cc.y >> 24) & 0xff);
    } else {
      int4 cb0 = ((const int4*)cens)[v];
      int4 cb1 = ((const int4*)cens)[v + 1];
      acc += proc4(e0, s0, t0, h0, b0, cb0.x, cb0.y, cb0.z, cb0.w);
      acc += proc4(e1, s1, t1, h1, b1, cb1.x, cb1.y, cb1.z, cb1.w);
    }
  }
  // In-chunk tail (vcnt not divisible by 512): single-vec4 steps.
  for (int vv = v0 + full * per_iter + threadIdx.x; vv < v0 + vcnt;
       vv += NTHREADS) {
    float4 e = pe[vv], s = ps[vv], t = tg[vv], h = th[vv];
    int4 b = bid[vv];
    int c0, c1, c2, c3;
    if (is8) {
      uchar4 c = ((const uchar4*)cens)[vv];
      c0 = c.x; c1 = c.y; c2 = c.z; c3 = c.w;
    } else {
      int4 c = ((const int4*)cens)[vv];
      c0 = c.x; c1 = c.y; c2 = c.z; c3 = c.w;
    }
    acc += proc4(e, s, t, h, b, c0, c1, c2, c3);
  }
  // Global scalar tail: vec4s beyond gridDim*vcnt, plus n%4 elements.
  for (int idx = (int)(gridDim.x * vcnt) * 4 + blockIdx.x * NTHREADS + threadIdx.x;
       idx < n; idx += gridDim.x * NTHREADS) {
    float pev = ((const float*)pe)[idx];
    float psv = ((const float*)ps)[idx];
    float tgv = ((const float*)tg)[idx];
    float thv = ((const float*)th)[idx];
    int bv = ((const int*)bid)[idx];
    int cv = is8 ? (int)((const unsigned char*)cens)[idx]
                 : ((const int*)cens)[idx];
    acc += per_sample(pev, psv, tgv, thv, bv, cv);
  }

  // ---- block reduction ----
  for (int off = 32; off > 0; off >>= 1) acc += __shfl_down(acc, off, 64);
  __shared__ float wsum[NTHREADS / 64];
  const int lane = threadIdx.x & 63;
  const int wid = threadIdx.x >> 6;
  if (lane == 0) wsum[wid] = acc;
  __syncthreads();

  // ---- last-block finalize (ticket; all HW-native ops) ----
  __shared__ int sdone;
  if (threadIdx.x == 0) {
    float b = 0.0f;
    for (int w = 0; w < NTHREADS / 64; ++w) b += wsum[w];
    partials[blockIdx.x] = b;   // plain store
    __threadfence();            // release: partial visible device-wide
    unsigned t = atomicAdd(counter, 1u);  // u32 HW atomic, one per block
    sdone = (t == gridDim.x - 1);
  }
  __syncthreads();
  if (sdone) {
    __threadfence();  // acquire
    double dacc = 0.0;
    for (int i = threadIdx.x; i < (int)gridDim.x; i += NTHREADS) {
      // Native f32 atomic-add(0) = device-coherent read; distinct addresses.
      dacc += (double)atomicAdd(&partials[i], 0.0f);
    }
    for (int off = 32; off > 0; off >>= 1) dacc += __shfl_down(dacc, off, 64);
    __shared__ double dsum[NTHREADS / 64];
    if (lane == 0) dsum[wid] = dacc;
    __syncthreads();
    if (threadIdx.x == 0) {
      double s = 0.0;
      for (int w = 0; w < NTHREADS / 64; ++w) s += dsum[w];
      out[0] = (float)(s * inv_n);
    }
  }
}

extern "C" void kernel_launch(void* const* d_in, const int* in_sizes, int n_in,
                              void* d_out, int out_size, void* d_ws, size_t ws_size,
                              hipStream_t stream) {
  const float* pe = (const float*)d_in[0];
  const float* ps = (const float*)d_in[1];
  const float* tg = (const float*)d_in[2];
  const int* bid = (const int*)d_in[3];
  const void* cens = d_in[4];
  const float* th = (const float*)d_in[5];
  const int n = in_sizes[0];

  float* partials = (float*)d_ws;
  unsigned* counter = (unsigned*)((char*)d_ws + NBLOCKS * sizeof(float));

  // Reset ticket each call (graph-capturable async memset; proven R3).
  hipMemsetAsync(counter, 0, sizeof(unsigned), stream);

  dualhead_fused<<<NBLOCKS, NTHREADS, 0, stream>>>(
      (const float4*)pe, (const float4*)ps, (const float4*)tg,
      (const int4*)bid, cens, (const float4*)th, partials, counter,
      (float*)d_out, n, 1.0 / (double)n);
}